// Round 1
// baseline (269.849 us; speedup 1.0000x reference)
//
#include <hip/hip_runtime.h>

// SpectralConv3d: closed-form separable transforms (no FFT needed).
// fwd:  X[bc,k1,k2,k3] = sum_{j1,j2,j3} T[k1,j1]T[k2,j2]T[k3,j3] x[bc,j1,j2,j3]
//       T[k,j] = w_j cos(2*pi*j*k/126), w_0=w_63=1 else 2   (k<16, j<64)
// mix:  low[b,o,m] = sum_i X[b,i,m] W[i,o,m]
// inv:  out_re/im = low contracted with cosA (p1), cosA (p2), cosB/sinB (p3)
//       cosA[p,j]=cos(2pi j p/64)/64 (p<33), cosB/sinB[p,j]=cos/sin(2pi j p/33)/33 (p<17)

#define PI2 6.283185307179586476925f

// ---------------- init: transform matrices into workspace ----------------
// Tt is T transposed ([j][k], 64x16) so phase-1 of k_fwd12 can s_load
// contiguous k-quads at wave-uniform addresses.
__global__ void k_init(float* __restrict__ Tmat, float* __restrict__ Tt,
                       float* __restrict__ cA, float* __restrict__ cB,
                       float* __restrict__ sB) {
    int t = blockIdx.x * 256 + threadIdx.x;
    if (t < 1024) {
        int k = t >> 6, j = t & 63;
        float w = (j == 0 || j == 63) ? 1.f : 2.f;
        int r = (j * k) % 126;
        float v = w * cosf(PI2 * (float)r / 126.f);
        Tmat[t] = v;
        Tt[j * 16 + k] = v;
    }
    if (t < 528) {
        int p = t >> 4, j = t & 15;
        int r = (j * p) % 64;
        cA[t] = cosf(PI2 * (float)r / 64.f) * (1.f / 64.f);
    }
    if (t < 272) {
        int p = t >> 4, j = t & 15;
        int r = (j * p) % 33;
        float a = PI2 * (float)r / 33.f;
        cB[t] = cosf(a) * (1.f / 33.f);
        sB[t] = sinf(a) * (1.f / 33.f);
    }
}

// ---------------- fused forward: contract j3 then j2 per (bc, j1) ----------------
// phase1: wave w owns k3 in {4w..4w+3} (wave-uniform -> T via s_load, scalar K$),
//         lane = j2 (64 lanes). 16 ds_read_b128 + 4 ds_write_b32 per wave
//         (was 80 reads). phase2 unchanged.
__global__ __launch_bounds__(256) void k_fwd12(const float* __restrict__ x,
                                               const float* __restrict__ Tmat,
                                               const float* __restrict__ Tt,
                                               float* __restrict__ A2) {
    __shared__ float xt[64 * 68];   // [j2][j3] padded stride 68 (17 float4)
    __shared__ float Ts[16 * 68];   // T row-major padded (phase2 operand)
    __shared__ float tmp[16 * 68];  // tmp[k3][j2], padded
    const int j1 = blockIdx.x, bc = blockIdx.y;
    const int t = threadIdx.x;

    float4* xt4 = (float4*)xt;
    float4* Ts4 = (float4*)Ts;
    const float4* xg = (const float4*)(x + ((size_t)bc * 64 + j1) * 4096);
    for (int c = t; c < 1024; c += 256) {
        int j2 = c >> 4, q = c & 15;
        xt4[j2 * 17 + q] = xg[c];
    }
    {
        const float4* Tg = (const float4*)Tmat;
        int k = t >> 4, q = t & 15;
        Ts4[k * 17 + q] = Tg[t];
    }
    __syncthreads();

    // phase 1: tmp[k3][j2] = sum_j3 xt[j2][j3] * T[k3][j3]
    // lane j2 = t&63; wave-uniform w = t>>6 selects the k3 quad.
    {
        const int j2 = t & 63;
        const int w = __builtin_amdgcn_readfirstlane(t >> 6);
        const float4* Tt4 = (const float4*)Tt;  // Tt4[j3*4 + kq] = T[4kq..4kq+3][j3]
        float a0 = 0.f, a1 = 0.f, a2 = 0.f, a3 = 0.f;
#pragma unroll 4
        for (int q = 0; q < 16; q++) {
            float4 xv = xt4[j2 * 17 + q];
            float4 t0 = Tt4[(4 * q + 0) * 4 + w];   // uniform addr -> s_load
            float4 t1 = Tt4[(4 * q + 1) * 4 + w];
            float4 t2 = Tt4[(4 * q + 2) * 4 + w];
            float4 t3 = Tt4[(4 * q + 3) * 4 + w];
            a0 += xv.x * t0.x + xv.y * t1.x + xv.z * t2.x + xv.w * t3.x;
            a1 += xv.x * t0.y + xv.y * t1.y + xv.z * t2.y + xv.w * t3.y;
            a2 += xv.x * t0.z + xv.y * t1.z + xv.z * t2.z + xv.w * t3.z;
            a3 += xv.x * t0.w + xv.y * t1.w + xv.z * t2.w + xv.w * t3.w;
        }
        tmp[(4 * w + 0) * 68 + j2] = a0;
        tmp[(4 * w + 1) * 68 + j2] = a1;
        tmp[(4 * w + 2) * 68 + j2] = a2;
        tmp[(4 * w + 3) * 68 + j2] = a3;
    }
    __syncthreads();

    // phase 2: A2[k2][k3] = sum_j2 tmp[k3][j2] * T[k2][j2]
    {
        const int k3 = t & 15;
        const int k2 = t >> 4;
        const float4* tmp4 = (const float4*)tmp;
        float acc = 0.f;
#pragma unroll 4
        for (int q = 0; q < 16; q++) {
            float4 tv = tmp4[k3 * 17 + q];
            float4 Tv = Ts4[k2 * 17 + q];
            acc += tv.x * Tv.x + tv.y * Tv.y + tv.z * Tv.z + tv.w * Tv.w;
        }
        A2[((size_t)bc * 64 + j1) * 256 + t] = acc;  // k2*16+k3 == t, coalesced
    }
}

// ---------------- forward j1 contraction ----------------
__global__ __launch_bounds__(256) void k_fwd3(const float* __restrict__ A2,
                                              const float* __restrict__ Tmat,
                                              float* __restrict__ X) {
    __shared__ float Ts[128];
    const int k1g = blockIdx.x;  // 0..7 -> k1 = 2*k1g, 2*k1g+1
    const int bc = blockIdx.y;
    const int t = threadIdx.x;
    if (t < 128) Ts[t] = Tmat[k1g * 128 + t];
    __syncthreads();
    const float* Ap = A2 + (size_t)bc * 64 * 256 + t;
    float a0 = 0.f, a1 = 0.f;
#pragma unroll 8
    for (int j1 = 0; j1 < 64; j1++) {
        float v = Ap[j1 * 256];
        a0 += v * Ts[j1];
        a1 += v * Ts[64 + j1];
    }
    X[(size_t)bc * 4096 + (size_t)(k1g * 2) * 256 + t] = a0;
    X[(size_t)bc * 4096 + (size_t)(k1g * 2 + 1) * 256 + t] = a1;
}

// ---------------- channel mix ----------------
__global__ __launch_bounds__(256) void k_mix(const float* __restrict__ X,
                                             const float* __restrict__ W,
                                             float* __restrict__ low) {
    const int mc = blockIdx.x;  // 0..15
    const int o = blockIdx.y;   // 0..31
    const int m = mc * 256 + threadIdx.x;
    const float* Xp = X + m;
    const float* Wp = W + (size_t)o * 4096 + m;
    float acc[4] = {0.f, 0.f, 0.f, 0.f};
#pragma unroll 4
    for (int i = 0; i < 32; i++) {
        float wv = Wp[(size_t)i * 32 * 4096];
#pragma unroll
        for (int b = 0; b < 4; b++)
            acc[b] += Xp[(size_t)(b * 32 + i) * 4096] * wv;
    }
#pragma unroll
    for (int b = 0; b < 4; b++)
        low[((size_t)(b * 32 + o)) * 4096 + m] = acc[b];
}

// ---------------- inverse pass E: contract k1 (LDS-free) ----------------
// E[bo][p1][m23] = sum_k1 low[bo][k1*256+m23] * cA[p1*16+k1]
// Thread owns column m23 in 16 registers; cA is uniform -> s_load.
__global__ __launch_bounds__(256) void k_invE(const float* __restrict__ low,
                                              const float* __restrict__ cA,
                                              float* __restrict__ E) {
    const int bo = blockIdx.y;
    const int t = threadIdx.x;
    const float* lp = low + (size_t)bo * 4096 + t;
    float r[16];
#pragma unroll
    for (int k1 = 0; k1 < 16; k1++) r[k1] = lp[k1 * 256];  // coalesced 1KB/iter
    const int p1q = blockIdx.x;                       // quarters 9/8/8/8
    const int p1lo = p1q * 8 + (p1q > 0 ? 1 : 0);
    const int p1hi = p1q * 8 + 8;
    for (int p1 = p1lo; p1 <= p1hi; p1++) {
        float acc = 0.f;
#pragma unroll
        for (int k1 = 0; k1 < 16; k1++) acc += r[k1] * cA[p1 * 16 + k1];
        E[((size_t)bo * 33 + p1) * 256 + t] = acc;
    }
}

// ---------------- inverse pass F: contract k2 (LDS-free) ----------------
// F[bo][p1][p2][k3] = sum_k2 E[bo][p1][k2*16+k3] * cA[p2*16+k2]
__global__ __launch_bounds__(256) void k_invF(const float* __restrict__ E,
                                              const float* __restrict__ cA,
                                              float* __restrict__ F) {
    const int gid = blockIdx.x * 256 + threadIdx.x;   // 0..67583 = bo*528 + p1*16 + k3
    const int bo = gid / 528;
    const int rem = gid - bo * 528;
    const int p1 = rem >> 4;
    const int k3 = rem & 15;
    const float* ep = E + ((size_t)bo * 33 + p1) * 256 + k3;
    float r[16];
#pragma unroll
    for (int k2 = 0; k2 < 16; k2++) r[k2] = ep[k2 * 16];
    const int h = blockIdx.y;                         // p2 halves 17/16
    const int p2lo = h * 17;
    const int p2hi = h ? 32 : 16;
    float* fp = F + (((size_t)bo * 33 + p1) * 33) * 16 + k3;
    for (int p2 = p2lo; p2 <= p2hi; p2++) {
        float acc = 0.f;
#pragma unroll
        for (int k2 = 0; k2 < 16; k2++) acc += r[k2] * cA[p2 * 16 + k2];
        fp[(size_t)p2 * 16] = acc;
    }
}

// ---------------- inverse pass G: contract k3, emit re/im (LDS-free) ----------------
// out[bo][p1][p2][p3][cc] = sum_k3 F[bo][p1][p2][k3] * (cc? sB:cB)[p3*16+k3]
__global__ __launch_bounds__(256) void k_invG(const float* __restrict__ F,
                                              const float* __restrict__ cB,
                                              const float* __restrict__ sB,
                                              float* __restrict__ out) {
    const int gid = blockIdx.x * 256 + threadIdx.x;   // (bo,p1,p2) lexicographic
    if (gid >= 128 * 33 * 33) return;
    const float4* rf4 = (const float4*)(F + (size_t)gid * 16);
    float rf[16];
    float4 f;
    f = rf4[0]; rf[0] = f.x; rf[1] = f.y; rf[2] = f.z; rf[3] = f.w;
    f = rf4[1]; rf[4] = f.x; rf[5] = f.y; rf[6] = f.z; rf[7] = f.w;
    f = rf4[2]; rf[8] = f.x; rf[9] = f.y; rf[10] = f.z; rf[11] = f.w;
    f = rf4[3]; rf[12] = f.x; rf[13] = f.y; rf[14] = f.z; rf[15] = f.w;
    float* op = out + (size_t)gid * 34;
    for (int p3 = 0; p3 < 17; p3++) {
        float ac = 0.f, as = 0.f;
#pragma unroll
        for (int k3 = 0; k3 < 16; k3++) {
            ac += rf[k3] * cB[p3 * 16 + k3];
            as += rf[k3] * sB[p3 * 16 + k3];
        }
        op[p3 * 2] = ac;
        op[p3 * 2 + 1] = as;
    }
}

extern "C" void kernel_launch(void* const* d_in, const int* in_sizes, int n_in,
                              void* d_out, int out_size, void* d_ws, size_t ws_size,
                              hipStream_t stream) {
    const float* x = (const float*)d_in[0];   // (4,32,64,64,64)
    const float* W = (const float*)d_in[1];   // (32,32,16,16,16)
    float* out = (float*)d_out;               // (4,32,33,33,17,2)

    float* ws = (float*)d_ws;
    float* Tmat = ws;                 // 1024
    float* Tt   = ws + 1024;          // 1024 (T transposed, [j][k])
    float* cA   = ws + 2048;          // 528
    float* cB   = ws + 2576;          // 272
    float* sB   = ws + 2848;          // 272
    float* A2   = ws + 4096;          // 128*64*256 = 2097152
    float* X    = A2 + 2097152;       // 128*4096   = 524288
    float* low  = X + 524288;         // 128*4096   = 524288
    float* E    = low + 524288;       // 128*33*256 = 1081344
    float* F    = E + 1081344;        // 128*33*33*16 = 2230272

    k_init<<<dim3(4), dim3(256), 0, stream>>>(Tmat, Tt, cA, cB, sB);
    k_fwd12<<<dim3(64, 128), dim3(256), 0, stream>>>(x, Tmat, Tt, A2);
    k_fwd3<<<dim3(8, 128), dim3(256), 0, stream>>>(A2, Tmat, X);
    k_mix<<<dim3(16, 32), dim3(256), 0, stream>>>(X, W, low);
    k_invE<<<dim3(4, 128), dim3(256), 0, stream>>>(low, cA, E);
    k_invF<<<dim3(264, 2), dim3(256), 0, stream>>>(E, cA, F);
    k_invG<<<dim3(545), dim3(256), 0, stream>>>(F, cB, sB, out);
}

// Round 2
// 243.274 us; speedup vs baseline: 1.1092x; 1.1092x over previous
//
#include <hip/hip_runtime.h>

// SpectralConv3d: closed-form separable transforms (no FFT needed).
// fwd:  X[bc,k1,k2,k3] = sum_{j1,j2,j3} T[k1,j1]T[k2,j2]T[k3,j3] x[bc,j1,j2,j3]
//       T[k,j] = w_j cos(2*pi*j*k/126), w_0=w_63=1 else 2   (k<16, j<64)
// mix:  low[b,o,m] = sum_i X[b,i,m] W[i,o,m]
// inv:  out_re/im = low contracted with cosA (p1), cosA (p2), cosB/sinB (p3)
//       cosA[p,j]=cos(2pi j p/64)/64 (p<33), cosB/sinB[p,j]=cos/sin(2pi j p/33)/33 (p<17)

#define PI2 6.283185307179586476925f

// ---------------- init: transform matrices into workspace ----------------
__global__ void k_init(float* __restrict__ Tmat, float* __restrict__ cA,
                       float* __restrict__ cB, float* __restrict__ sB) {
    int t = blockIdx.x * 256 + threadIdx.x;
    if (t < 1024) {
        int k = t >> 6, j = t & 63;
        float w = (j == 0 || j == 63) ? 1.f : 2.f;
        int r = (j * k) % 126;
        Tmat[t] = w * cosf(PI2 * (float)r / 126.f);
    }
    if (t < 528) {
        int p = t >> 4, j = t & 15;
        int r = (j * p) % 64;
        cA[t] = cosf(PI2 * (float)r / 64.f) * (1.f / 64.f);
    }
    if (t < 272) {
        int p = t >> 4, j = t & 15;
        int r = (j * p) % 33;
        float a = PI2 * (float)r / 33.f;
        cB[t] = cosf(a) * (1.f / 33.f);
        sB[t] = sinf(a) * (1.f / 33.f);
    }
}

// ---------------- fused forward: contract j3 then j2 per (bc, j1) ----------------
// (round-0 proven version: broadcast-dedup'd LDS reads, HBM-bound)
__global__ __launch_bounds__(256) void k_fwd12(const float* __restrict__ x,
                                               const float* __restrict__ Tmat,
                                               float* __restrict__ A2) {
    __shared__ float xt[64 * 68];   // padded stride 68 (17 float4) -> <=2-way
    __shared__ float Ts[16 * 68];
    __shared__ float tmp[16 * 68];  // tmp[k3][j2], padded
    const int j1 = blockIdx.x, bc = blockIdx.y;
    const int t = threadIdx.x;

    float4* xt4 = (float4*)xt;
    float4* Ts4 = (float4*)Ts;
    const float4* xg = (const float4*)(x + ((size_t)bc * 64 + j1) * 4096);
    for (int c = t; c < 1024; c += 256) {
        int j2 = c >> 4, q = c & 15;
        xt4[j2 * 17 + q] = xg[c];
    }
    if (t < 256) {
        const float4* Tg = (const float4*)Tmat;
        int k = t >> 4, q = t & 15;
        Ts4[k * 17 + q] = Tg[t];
    }
    __syncthreads();

    // phase 1: tmp[k3][j2] = sum_j3 xt[j2][j3] * T[k3][j3]
    {
        const int j2 = (t & 15) + 16 * (t >> 6);
        const int k3b = (t >> 4) & 3;
        float acc[4] = {0.f, 0.f, 0.f, 0.f};
#pragma unroll 4
        for (int q = 0; q < 16; q++) {
            float4 xv = xt4[j2 * 17 + q];
#pragma unroll
            for (int c = 0; c < 4; c++) {
                float4 tv = Ts4[(k3b + 4 * c) * 17 + q];
                acc[c] += xv.x * tv.x + xv.y * tv.y + xv.z * tv.z + xv.w * tv.w;
            }
        }
#pragma unroll
        for (int c = 0; c < 4; c++)
            tmp[(k3b + 4 * c) * 68 + j2] = acc[c];
    }
    __syncthreads();

    // phase 2: A2[k2][k3] = sum_j2 tmp[k3][j2] * T[k2][j2]
    {
        const int k3 = t & 15;
        const int k2 = t >> 4;
        const float4* tmp4 = (const float4*)tmp;
        float acc = 0.f;
#pragma unroll 4
        for (int q = 0; q < 16; q++) {
            float4 tv = tmp4[k3 * 17 + q];
            float4 Tv = Ts4[k2 * 17 + q];
            acc += tv.x * Tv.x + tv.y * Tv.y + tv.z * Tv.z + tv.w * Tv.w;
        }
        A2[((size_t)bc * 64 + j1) * 256 + t] = acc;  // k2*16+k3 == t, coalesced
    }
}

// ---------------- forward j1 contraction ----------------
// X[bc][k1][m23] = sum_j1 A2[bc][j1][m23] * T[k1][j1]
// NEW: 8 k1-accumulators per thread -> A2 read 2x (16.8 MB) instead of 8x (67 MB).
// Tst staged transposed [j1][8k1] so inner loop = 2 broadcast ds_read_b128 per j1.
__global__ __launch_bounds__(256) void k_fwd3(const float* __restrict__ A2,
                                              const float* __restrict__ Tmat,
                                              float* __restrict__ X) {
    __shared__ float Tst[512];  // [j1][c], c = k1 - 8*k1h
    const int k1h = blockIdx.x;  // 0..1
    const int bc = blockIdx.y;
    const int t = threadIdx.x;
    for (int c0 = t; c0 < 512; c0 += 256) {
        int j1 = c0 >> 3, c = c0 & 7;
        Tst[c0] = Tmat[(size_t)(k1h * 8 + c) * 64 + j1];
    }
    __syncthreads();
    const float* Ap = A2 + (size_t)bc * 64 * 256 + t;
    float acc[8] = {0.f, 0.f, 0.f, 0.f, 0.f, 0.f, 0.f, 0.f};
#pragma unroll 8
    for (int j1 = 0; j1 < 64; j1++) {
        float v = Ap[j1 * 256];
        float4 t0 = *(const float4*)&Tst[j1 * 8];
        float4 t1 = *(const float4*)&Tst[j1 * 8 + 4];
        acc[0] += v * t0.x; acc[1] += v * t0.y; acc[2] += v * t0.z; acc[3] += v * t0.w;
        acc[4] += v * t1.x; acc[5] += v * t1.y; acc[6] += v * t1.z; acc[7] += v * t1.w;
    }
    float* Xp = X + (size_t)bc * 4096 + (size_t)(k1h * 8) * 256 + t;
#pragma unroll
    for (int c = 0; c < 8; c++) Xp[(size_t)c * 256] = acc[c];
}

// ---------------- channel mix ----------------
// low[b,o,m] = sum_i X[b*32+i][m] * W[(i*32+o)][m]
__global__ __launch_bounds__(256) void k_mix(const float* __restrict__ X,
                                             const float* __restrict__ W,
                                             float* __restrict__ low) {
    const int mc = blockIdx.x;  // 0..15
    const int o = blockIdx.y;   // 0..31
    const int m = mc * 256 + threadIdx.x;
    const float* Xp = X + m;
    const float* Wp = W + (size_t)o * 4096 + m;
    float acc[4] = {0.f, 0.f, 0.f, 0.f};
#pragma unroll 4
    for (int i = 0; i < 32; i++) {
        float wv = Wp[(size_t)i * 32 * 4096];
#pragma unroll
        for (int b = 0; b < 4; b++)
            acc[b] += Xp[(size_t)(b * 32 + i) * 4096] * wv;
    }
#pragma unroll
    for (int b = 0; b < 4; b++)
        low[((size_t)(b * 32 + o)) * 4096 + m] = acc[b];
}

// ---------------- fused inverse per (bo, p1) ----------------
__global__ __launch_bounds__(256) void k_inv(const float* __restrict__ low,
                                             const float* __restrict__ cA,
                                             const float* __restrict__ cB,
                                             const float* __restrict__ sB,
                                             float* __restrict__ out) {
    __shared__ float lt[4096];
    __shared__ float c1[256];
    __shared__ float c2[528];
    __shared__ float cAs[528], cBs[272], sBs[272];
    const int p1 = blockIdx.x, bo = blockIdx.y;
    const int t = threadIdx.x;

    float4* lt4 = (float4*)lt;
    const float4* lg = (const float4*)(low + (size_t)bo * 4096);
    for (int c = t; c < 1024; c += 256) lt4[c] = lg[c];
    for (int c = t; c < 528; c += 256) cAs[c] = cA[c];
    for (int c = t; c < 272; c += 256) { cBs[c] = cB[c]; sBs[c] = sB[c]; }
    __syncthreads();

    // E: c1[k2*16+k3] = sum_k1 low[k1][k2k3] * cosA[p1][k1]
    {
        float acc = 0.f;
#pragma unroll
        for (int k1 = 0; k1 < 16; k1++) acc += lt[(k1 << 8) + t] * cAs[p1 * 16 + k1];
        c1[t] = acc;
    }
    __syncthreads();

    // F: c2[p2*16+k3] = sum_k2 c1[k2*16+k3] * cosA[p2][k2]
    for (int idx = t; idx < 528; idx += 256) {
        int p2 = idx >> 4, k3 = idx & 15;
        float acc = 0.f;
#pragma unroll
        for (int k2 = 0; k2 < 16; k2++) acc += c1[(k2 << 4) + k3] * cAs[p2 * 16 + k2];
        c2[idx] = acc;
    }
    __syncthreads();

    // G: out[p2][p3][{re,im}] = sum_k3 c2[p2][k3] * cosB/sinB[p3][k3]
    float* op = out + ((size_t)bo * 33 + p1) * 33 * 17 * 2;
    for (int idx = t; idx < 1122; idx += 256) {
        int p2 = idx / 34, rem = idx % 34;
        int p3 = rem >> 1, cc = rem & 1;
        const float* M = cc ? sBs : cBs;
        float acc = 0.f;
#pragma unroll
        for (int k3 = 0; k3 < 16; k3++) acc += c2[(p2 << 4) + k3] * M[p3 * 16 + k3];
        op[idx] = acc;
    }
}

extern "C" void kernel_launch(void* const* d_in, const int* in_sizes, int n_in,
                              void* d_out, int out_size, void* d_ws, size_t ws_size,
                              hipStream_t stream) {
    const float* x = (const float*)d_in[0];   // (4,32,64,64,64)
    const float* W = (const float*)d_in[1];   // (32,32,16,16,16)
    float* out = (float*)d_out;               // (4,32,33,33,17,2)

    float* ws = (float*)d_ws;
    float* Tmat = ws;                 // 1024
    float* cA   = ws + 1024;          // 528
    float* cB   = ws + 1552;          // 272
    float* sB   = ws + 1824;          // 272
    float* A2   = ws + 4096;          // 128*64*256 = 2097152
    float* X    = A2 + 2097152;       // 128*4096   = 524288
    float* low  = X + 524288;         // 128*4096   = 524288

    k_init<<<dim3(4), dim3(256), 0, stream>>>(Tmat, cA, cB, sB);
    k_fwd12<<<dim3(64, 128), dim3(256), 0, stream>>>(x, Tmat, A2);
    k_fwd3<<<dim3(2, 128), dim3(256), 0, stream>>>(A2, Tmat, X);
    k_mix<<<dim3(16, 32), dim3(256), 0, stream>>>(X, W, low);
    k_inv<<<dim3(33, 128), dim3(256), 0, stream>>>(low, cA, cB, sB, out);
}

// Round 3
// 239.191 us; speedup vs baseline: 1.1282x; 1.0171x over previous
//
#include <hip/hip_runtime.h>

// SpectralConv3d: closed-form separable transforms (no FFT needed).
// fwd:  X[bc,k1,k2,k3] = sum_{j1,j2,j3} T[k1,j1]T[k2,j2]T[k3,j3] x[bc,j1,j2,j3]
//       T[k,j] = w_j cos(2*pi*j*k/126), w_0=w_63=1 else 2   (k<16, j<64)
// mix:  low[b,o,m] = sum_i X[b,i,m] W[i,o,m]
// inv:  out_re/im = low contracted with cosA (p1), cosA (p2), cosB/sinB (p3)
//       cosA[p,j]=cos(2pi j p/64)/64 (p<33), cosB/sinB[p,j]=cos/sin(2pi j p/33)/33 (p<17)
//
// Tables are computed in-kernel (identical cosf expressions -> bit-identical
// results); k_init is gone. fwd12's block (0,0) publishes cA/cB/sB for k_inv
// (stream order guarantees visibility).

#define PI2 6.283185307179586476925f

// ---------------- fused forward: contract j3 then j2 per (bc, j1) ----------------
// phase 1 uses 2x2 register blocking: 4 ds_read_b128 per q per wave (was 5).
__global__ __launch_bounds__(256) void k_fwd12(const float* __restrict__ x,
                                               float* __restrict__ A2,
                                               float* __restrict__ cA,
                                               float* __restrict__ cB,
                                               float* __restrict__ sB) {
    __shared__ float xt[64 * 68];   // [j2][j3] padded stride 68 (17 float4)
    __shared__ float Ts[16 * 68];
    __shared__ float tmp[16 * 68];  // tmp[k3][j2], padded
    const int j1 = blockIdx.x, bc = blockIdx.y;
    const int t = threadIdx.x;

    float4* xt4 = (float4*)xt;
    float4* Ts4 = (float4*)Ts;
    const float4* xg = (const float4*)(x + ((size_t)bc * 64 + j1) * 4096);
    for (int c = t; c < 1024; c += 256) {
        int j2 = c >> 4, q = c & 15;
        xt4[j2 * 17 + q] = xg[c];
    }
    // compute T tile in-LDS (bit-identical to the old k_init formula)
    {
        int k = t >> 4, q = t & 15;
        float4 tv;
        float* tp = (float*)&tv;
#pragma unroll
        for (int e = 0; e < 4; e++) {
            int j = 4 * q + e;
            float w = (j == 0 || j == 63) ? 1.f : 2.f;
            int r = (j * k) % 126;
            tp[e] = w * cosf(PI2 * (float)r / 126.f);
        }
        Ts4[k * 17 + q] = tv;
    }
    // one block publishes the inverse-transform tables for k_inv
    if (j1 == 0 && bc == 0) {
        for (int c = t; c < 528; c += 256) {
            int p = c >> 4, j = c & 15;
            int r = (j * p) % 64;
            cA[c] = cosf(PI2 * (float)r / 64.f) * (1.f / 64.f);
        }
        for (int c = t; c < 272; c += 256) {
            int p = c >> 4, j = c & 15;
            int r = (j * p) % 33;
            float a = PI2 * (float)r / 33.f;
            cB[c] = cosf(a) * (1.f / 33.f);
            sB[c] = sinf(a) * (1.f / 33.f);
        }
    }
    __syncthreads();

    // phase 1: tmp[k3][j2] = sum_j3 xt[j2][j3] * T[k3][j3]
    // thread owns j2 in {j2l, j2l+32}, k3 in {k3l, k3l+8}
    {
        const int j2l = t & 31;
        const int k3l = t >> 5;   // 0..7
        float a00 = 0.f, a01 = 0.f, a10 = 0.f, a11 = 0.f;
#pragma unroll 4
        for (int q = 0; q < 16; q++) {
            float4 x0 = xt4[j2l * 17 + q];
            float4 x1 = xt4[(j2l + 32) * 17 + q];
            float4 t0 = Ts4[k3l * 17 + q];
            float4 t1 = Ts4[(k3l + 8) * 17 + q];
            a00 += x0.x * t0.x + x0.y * t0.y + x0.z * t0.z + x0.w * t0.w;
            a01 += x0.x * t1.x + x0.y * t1.y + x0.z * t1.z + x0.w * t1.w;
            a10 += x1.x * t0.x + x1.y * t0.y + x1.z * t0.z + x1.w * t0.w;
            a11 += x1.x * t1.x + x1.y * t1.y + x1.z * t1.z + x1.w * t1.w;
        }
        tmp[k3l * 68 + j2l] = a00;
        tmp[(k3l + 8) * 68 + j2l] = a01;
        tmp[k3l * 68 + j2l + 32] = a10;
        tmp[(k3l + 8) * 68 + j2l + 32] = a11;
    }
    __syncthreads();

    // phase 2: A2[k2][k3] = sum_j2 tmp[k3][j2] * T[k2][j2]
    {
        const int k3 = t & 15;
        const int k2 = t >> 4;
        const float4* tmp4 = (const float4*)tmp;
        float acc = 0.f;
#pragma unroll 4
        for (int q = 0; q < 16; q++) {
            float4 tv = tmp4[k3 * 17 + q];
            float4 Tv = Ts4[k2 * 17 + q];
            acc += tv.x * Tv.x + tv.y * Tv.y + tv.z * Tv.z + tv.w * Tv.w;
        }
        A2[((size_t)bc * 64 + j1) * 256 + t] = acc;  // k2*16+k3 == t, coalesced
    }
}

// ---------------- forward j1 contraction ----------------
// X[bc][k1][m23] = sum_j1 A2[bc][j1][m23] * T[k1][j1]
// 8 k1-accumulators per thread; Tst computed in-LDS (bit-identical cosf).
__global__ __launch_bounds__(256) void k_fwd3(const float* __restrict__ A2,
                                              float* __restrict__ X) {
    __shared__ float Tst[512];  // [j1][c], c = k1 - 8*k1h
    const int k1h = blockIdx.x;  // 0..1
    const int bc = blockIdx.y;
    const int t = threadIdx.x;
    for (int c0 = t; c0 < 512; c0 += 256) {
        int j1 = c0 >> 3, c = c0 & 7;
        int k1 = k1h * 8 + c;
        float w = (j1 == 0 || j1 == 63) ? 1.f : 2.f;
        int r = (j1 * k1) % 126;
        Tst[c0] = w * cosf(PI2 * (float)r / 126.f);
    }
    __syncthreads();
    const float* Ap = A2 + (size_t)bc * 64 * 256 + t;
    float acc[8] = {0.f, 0.f, 0.f, 0.f, 0.f, 0.f, 0.f, 0.f};
#pragma unroll 8
    for (int j1 = 0; j1 < 64; j1++) {
        float v = Ap[j1 * 256];
        float4 t0 = *(const float4*)&Tst[j1 * 8];
        float4 t1 = *(const float4*)&Tst[j1 * 8 + 4];
        acc[0] += v * t0.x; acc[1] += v * t0.y; acc[2] += v * t0.z; acc[3] += v * t0.w;
        acc[4] += v * t1.x; acc[5] += v * t1.y; acc[6] += v * t1.z; acc[7] += v * t1.w;
    }
    float* Xp = X + (size_t)bc * 4096 + (size_t)(k1h * 8) * 256 + t;
#pragma unroll
    for (int c = 0; c < 8; c++) Xp[(size_t)c * 256] = acc[c];
}

// ---------------- channel mix ----------------
// low[b,o,m] = sum_i X[b*32+i][m] * W[(i*32+o)][m]
// 2 o's per block: X re-reads halved, W still read exactly once.
__global__ __launch_bounds__(256) void k_mix(const float* __restrict__ X,
                                             const float* __restrict__ W,
                                             float* __restrict__ low) {
    const int mc = blockIdx.x;   // 0..15
    const int og = blockIdx.y;   // 0..15 -> o = 2*og, 2*og+1
    const int m = mc * 256 + threadIdx.x;
    const float* Xp = X + m;
    const float* Wp = W + (size_t)(og * 2) * 4096 + m;
    float acc[4][2] = {{0.f,0.f},{0.f,0.f},{0.f,0.f},{0.f,0.f}};
#pragma unroll 4
    for (int i = 0; i < 32; i++) {
        float w0 = Wp[(size_t)(i * 32) * 4096];
        float w1 = Wp[(size_t)(i * 32 + 1) * 4096];
#pragma unroll
        for (int b = 0; b < 4; b++) {
            float xv = Xp[(size_t)(b * 32 + i) * 4096];
            acc[b][0] += xv * w0;
            acc[b][1] += xv * w1;
        }
    }
#pragma unroll
    for (int b = 0; b < 4; b++) {
        low[((size_t)(b * 32 + og * 2)) * 4096 + m] = acc[b][0];
        low[((size_t)(b * 32 + og * 2 + 1)) * 4096 + m] = acc[b][1];
    }
}

// ---------------- fused inverse, 3 p1 per block ----------------
__global__ __launch_bounds__(256) void k_inv(const float* __restrict__ low,
                                             const float* __restrict__ cA,
                                             const float* __restrict__ cB,
                                             const float* __restrict__ sB,
                                             float* __restrict__ out) {
    __shared__ float lt[4096];
    __shared__ float c1[3 * 256];
    __shared__ float c2[3 * 528];
    __shared__ float cAs[528], cBs[272], sBs[272];
    const int p1b = blockIdx.x * 3;   // 0,3,...,30 (11 blocks -> 33 p1)
    const int bo = blockIdx.y;
    const int t = threadIdx.x;

    float4* lt4 = (float4*)lt;
    const float4* lg = (const float4*)(low + (size_t)bo * 4096);
    for (int c = t; c < 1024; c += 256) lt4[c] = lg[c];
    for (int c = t; c < 528; c += 256) cAs[c] = cA[c];
    for (int c = t; c < 272; c += 256) { cBs[c] = cB[c]; sBs[c] = sB[c]; }
    __syncthreads();

    // E: c1[s][k2*16+k3] = sum_k1 low[k1][k2k3] * cosA[p1b+s][k1]  (lt read once)
    {
        float e0 = 0.f, e1 = 0.f, e2 = 0.f;
#pragma unroll
        for (int k1 = 0; k1 < 16; k1++) {
            float v = lt[(k1 << 8) + t];
            e0 += v * cAs[(p1b + 0) * 16 + k1];
            e1 += v * cAs[(p1b + 1) * 16 + k1];
            e2 += v * cAs[(p1b + 2) * 16 + k1];
        }
        c1[t] = e0; c1[256 + t] = e1; c1[512 + t] = e2;
    }
    __syncthreads();

    // F: c2[s][p2*16+k3] = sum_k2 c1[s][k2*16+k3] * cosA[p2][k2]
    for (int idx = t; idx < 528; idx += 256) {
        int p2 = idx >> 4, k3 = idx & 15;
        float f0 = 0.f, f1 = 0.f, f2 = 0.f;
#pragma unroll
        for (int k2 = 0; k2 < 16; k2++) {
            float cv = cAs[p2 * 16 + k2];
            int a = (k2 << 4) + k3;
            f0 += c1[a] * cv;
            f1 += c1[256 + a] * cv;
            f2 += c1[512 + a] * cv;
        }
        c2[idx] = f0; c2[528 + idx] = f1; c2[1056 + idx] = f2;
    }
    __syncthreads();

    // G: out[p1b+s][p2][p3][{re,im}] = sum_k3 c2[s][p2][k3] * cosB/sinB[p3][k3]
    for (int s = 0; s < 3; s++) {
        float* op = out + ((size_t)bo * 33 + p1b + s) * 33 * 17 * 2;
        const float* c2p = c2 + s * 528;
        for (int idx = t; idx < 1122; idx += 256) {
            int p2 = idx / 34, rem = idx - p2 * 34;
            int p3 = rem >> 1, cc = rem & 1;
            const float* M = cc ? sBs : cBs;
            float acc = 0.f;
#pragma unroll
            for (int k3 = 0; k3 < 16; k3++) acc += c2p[(p2 << 4) + k3] * M[p3 * 16 + k3];
            op[idx] = acc;
        }
    }
}

extern "C" void kernel_launch(void* const* d_in, const int* in_sizes, int n_in,
                              void* d_out, int out_size, void* d_ws, size_t ws_size,
                              hipStream_t stream) {
    const float* x = (const float*)d_in[0];   // (4,32,64,64,64)
    const float* W = (const float*)d_in[1];   // (32,32,16,16,16)
    float* out = (float*)d_out;               // (4,32,33,33,17,2)

    float* ws = (float*)d_ws;
    float* cA   = ws;                 // 528
    float* cB   = ws + 528;           // 272
    float* sB   = ws + 800;           // 272
    float* A2   = ws + 4096;          // 128*64*256 = 2097152
    float* X    = A2 + 2097152;       // 128*4096   = 524288
    float* low  = X + 524288;         // 128*4096   = 524288

    k_fwd12<<<dim3(64, 128), dim3(256), 0, stream>>>(x, A2, cA, cB, sB);
    k_fwd3<<<dim3(2, 128), dim3(256), 0, stream>>>(A2, X);
    k_mix<<<dim3(16, 16), dim3(256), 0, stream>>>(X, W, low);
    k_inv<<<dim3(11, 128), dim3(256), 0, stream>>>(low, cA, cB, sB, out);
}